// Round 7
// baseline (276.044 us; speedup 1.0000x reference)
//
#include <hip/hip_runtime.h>
#include <stdint.h>

#define B_    1024
#define P_    100
#define N_    101
#define EMB_  128
#define H_    8
#define DK_   16

#define ROWS  112          // 7 m-tiles of 16 (covers P=100 / N=101)
#define KSTR  136          // LDS row stride in bf16 elems

typedef uint16_t bf16;
typedef __attribute__((ext_vector_type(8))) short short8;
typedef __attribute__((ext_vector_type(4))) float float4v;

struct F4 { float x, y, z, w; };   // 4-byte-aligned float quad (101-stride safe)

#define L2E 1.4426950408889634f

#if __has_builtin(__builtin_amdgcn_exp2f)
#define EXP2(x) __builtin_amdgcn_exp2f(x)
#else
#define EXP2(x) exp2f(x)
#endif
#if __has_builtin(__builtin_amdgcn_rcpf)
#define RCP(x) __builtin_amdgcn_rcpf(x)
#else
#define RCP(x) (1.0f / (x))
#endif

__device__ __forceinline__ float b2f(bf16 u) {
    union { uint32_t i; float f; } c; c.i = ((uint32_t)u) << 16; return c.f;
}
// round-half-up f32->bf16 (bias then take high 16): 2 ops
__device__ __forceinline__ bf16 f2b(float f) {
    union { float f; uint32_t i; } c; c.f = f;
    return (bf16)((c.i + 0x8000u) >> 16);
}
// packed pair via v_perm byte-select: 3 ops for 2 values
__device__ __forceinline__ uint32_t pk2(float a, float b) {
    union { float f; uint32_t i; } ca, cb; ca.f = a; cb.f = b;
    return __builtin_amdgcn_perm(cb.i + 0x8000u, ca.i + 0x8000u, 0x07060302u);
}

// stage f32 [nrows][128] row-major -> bf16 LDS [ROWS][KSTR], zero pad rows
__device__ __forceinline__ void stage_m(const float* __restrict__ src, int nrows,
                                        bf16* __restrict__ dst, int tid) {
    for (int i = tid; i < ROWS * 32; i += 1024) {
        int r = i >> 5, c = (i & 31) << 2;
        uint32_t p0 = 0, p1 = 0;
        if (r < nrows) {
            float4 v = *(const float4*)(src + (size_t)r * EMB_ + c);
            p0 = pk2(v.x, v.y); p1 = pk2(v.z, v.w);
        }
        uint32_t* d = (uint32_t*)(dst + r * KSTR + c);
        d[0] = p0; d[1] = p1;
    }
}

// ---- prep: W f32 [k][o] -> ws bf16 W^T [o][k], order: Wk, Wv, Wq, Wc ------
__global__ __launch_bounds__(256)
void prep_wT(const float* __restrict__ Wq, const float* __restrict__ Wk,
             const float* __restrict__ Wv, const float* __restrict__ Wc,
             bf16* __restrict__ ws) {
    int idx = blockIdx.x * 256 + threadIdx.x;      // 65536 threads
    int w = idx >> 14, rem = idx & 16383;
    int k = rem >> 7, o = rem & 127;               // o innermost: coalesced read
    const float* W = (w == 0) ? Wk : (w == 1) ? Wv : (w == 2) ? Wq : Wc;
    ws[((size_t)w << 14) + o * 128 + k] = f2b(W[(size_t)k * 128 + o]);
}

__global__ __launch_bounds__(1024, 4)
void vrp_kernel(const float* __restrict__ eln,
                const float* __restrict__ load_,
                const float* __restrict__ time_,
                const float* __restrict__ len_,
                const float* __restrict__ open_,
                const float* __restrict__ mask_,
                const float* __restrict__ enc_,
                const float* __restrict__ Wq,
                const float* __restrict__ bc,
                const bf16* __restrict__ wsWT,
                float* __restrict__ out)
{
    const int b    = blockIdx.x;
    const int tid  = threadIdx.x;
    const int wave = tid >> 6;
    const int lane = tid & 63;
    const int lr = lane & 15, lq = lane >> 4, lk = lq << 3;

    // Overlays: R1 enc (live to F) ; R2 K/mh-lo ; R3 V^T ; R4 Q/O ; R5 cat/mh-hi
    __shared__ bf16 smem[78336];
    __shared__ float sS4[ROWS * 4];
    __shared__ float sWq4[4 * EMB_];
    bf16* const R1 = smem;
    bf16* const R2 = smem + 15232;
    bf16* const R3 = smem + 30464;
    bf16* const R4 = smem + 47872;
    bf16* const R5 = smem + 63104;

    const bf16* WkT = wsWT;
    const bf16* WvT = wsWT + 16384;
    const bf16* WqT = wsWT + 32768;
    const bf16* WcT = wsWT + 49152;

    const float* encB  = enc_  + (size_t)b * N_ * EMB_;
    const float* elnB  = eln   + (size_t)b * P_ * EMB_;
    const float* maskB = mask_ + (size_t)b * P_ * N_;
    float*       outB  = out   + (size_t)b * P_ * N_;

    // ---------------- Phase A: stage enc->R1, cat->R5, extras --------------
    stage_m(encB, N_, R1, tid);
    stage_m(elnB, P_, R5, tid);
    if (tid < 512) {   // zero sVt[d][112..127]
        int d = tid >> 2, c = 112 + ((tid & 3) << 2);
        uint32_t* z = (uint32_t*)(R3 + d * KSTR + c);
        z[0] = 0; z[1] = 0;
    }
    if (tid < ROWS * 4) {
        int r = tid >> 2, j = tid & 3;
        float v = 0.f;
        if (r < P_) {
            const float* s4 = (j == 0) ? load_ : (j == 1) ? time_
                             : (j == 2) ? len_ : open_;
            v = s4[(size_t)b * P_ + r];
        }
        sS4[r * 4 + j] = v;
    }
    if (tid < 512) {
        int j = tid >> 7, c = tid & 127;
        sWq4[j * EMB_ + c] = Wq[(size_t)(EMB_ + j) * EMB_ + c];
    }
    __syncthreads();

    // ------- Phase B+C: K->R2, V^T->R3, Q'->R4 (one barrier window) --------
    // 16 waves = 8 col-tiles x 2 m-tile halves
    {
        const int col = 16 * (wave & 7) + lr;
        const int mt0 = (wave >> 3) ? 4 : 0;
        const int mt1 = (wave >> 3) ? 7 : 4;
        short8 bk[4], bv[4], bq[4];
        {
            const bf16* rk = WkT + (size_t)col * 128 + lk;
            const bf16* rv = WvT + (size_t)col * 128 + lk;
            const bf16* rq = WqT + (size_t)col * 128 + lk;
            #pragma unroll
            for (int s = 0; s < 4; ++s) {
                bk[s] = *(const short8*)(rk + s * 32);
                bv[s] = *(const short8*)(rv + s * 32);
                bq[s] = *(const short8*)(rq + s * 32);
            }
        }
        float w0 = sWq4[col], w1 = sWq4[EMB_ + col];
        float w2 = sWq4[2 * EMB_ + col], w3 = sWq4[3 * EMB_ + col];
        for (int mt = mt0; mt < mt1; ++mt) {
            short8 a[4];
            #pragma unroll
            for (int s = 0; s < 4; ++s)
                a[s] = *(const short8*)(R1 + (mt * 16 + lr) * KSTR + s * 32 + lk);
            float4v ck = {0.f, 0.f, 0.f, 0.f}, cv = {0.f, 0.f, 0.f, 0.f};
            #pragma unroll
            for (int s = 0; s < 4; ++s) {
                ck = __builtin_amdgcn_mfma_f32_16x16x32_bf16(a[s], bk[s], ck, 0, 0, 0);
                cv = __builtin_amdgcn_mfma_f32_16x16x32_bf16(a[s], bv[s], cv, 0, 0, 0);
            }
            int n0 = mt * 16 + (lq << 2);
            #pragma unroll
            for (int r = 0; r < 4; ++r)
                R2[(n0 + r) * KSTR + col] = f2b(ck[r]);       // K [n][col]
            uint32_t* d = (uint32_t*)(R3 + col * KSTR + n0);  // V^T [d][n]
            d[0] = pk2(cv[0], cv[1]);
            d[1] = pk2(cv[2], cv[3]);
            // Q' = 0.25*log2e*(cat@Wq) for same mt  (log2e baked for exp2)
            short8 aq[4];
            #pragma unroll
            for (int s = 0; s < 4; ++s)
                aq[s] = *(const short8*)(R5 + (mt * 16 + lr) * KSTR + s * 32 + lk);
            float4v cq = {0.f, 0.f, 0.f, 0.f};
            #pragma unroll
            for (int s = 0; s < 4; ++s)
                cq = __builtin_amdgcn_mfma_f32_16x16x32_bf16(aq[s], bq[s], cq, 0, 0, 0);
            int row0 = mt * 16 + (lq << 2);
            #pragma unroll
            for (int r = 0; r < 4; ++r) {
                const float* s4 = sS4 + (row0 + r) * 4;
                float acc = cq[r] + s4[0] * w0 + s4[1] * w1 + s4[2] * w2 + s4[3] * w3;
                R4[(row0 + r) * KSTR + col] = f2b(acc * (0.25f * L2E));
            }
        }
    }
    __syncthreads();

    // -------- Phase D: attention; 14 waves = 7 p-tiles x 2 head-groups -----
    // Swapped QK^T: lane holds P[row=pt*16+lr][n=16nt+4lq+r] in registers.
    // P never touches LDS: PV A-fragments are assembled in-register via
    // ds_bpermute (8 shfl + 4 sel per k-window). No WAR between heads ->
    // the 4 unrolled heads software-pipeline; enc stays live in R1.
    const int hg = (wave >= 7) ? 1 : 0;
    const int pt = wave - hg * 7;
    float msk2[7][4];                 // reused by Phase F (waves 0-6)
    float4v o4[4];
    if (wave < 14) {
        // mask gather in swapped layout: row p = pt*16+lr, n = 16nt+4lq+r
        {
            const int p = pt * 16 + lr;
            const bool pvalid = (p < P_);
            const float* mrow = maskB + (size_t)(pvalid ? p : 0) * N_;
            #pragma unroll
            for (int nt = 0; nt < 6; ++nt) {        // n <= 95 < 101: packed
                int nb = nt * 16 + (lq << 2);
                F4 mv = *(const F4*)(mrow + nb);
                msk2[nt][0] = pvalid ? mv.x * L2E : 0.f;
                msk2[nt][1] = pvalid ? mv.y * L2E : 0.f;
                msk2[nt][2] = pvalid ? mv.z * L2E : 0.f;
                msk2[nt][3] = pvalid ? mv.w * L2E : 0.f;
            }
            // nt=6 tail: n = 96+4lq+r, valid only n<=100
            if (lq == 0) {
                F4 mv = *(const F4*)(mrow + 96);
                msk2[6][0] = pvalid ? mv.x * L2E : 0.f;
                msk2[6][1] = pvalid ? mv.y * L2E : 0.f;
                msk2[6][2] = pvalid ? mv.z * L2E : 0.f;
                msk2[6][3] = pvalid ? mv.w * L2E : 0.f;
            } else if (lq == 1) {
                msk2[6][0] = pvalid ? mrow[100] * L2E : 0.f;
                msk2[6][1] = -3.0e38f; msk2[6][2] = -3.0e38f; msk2[6][3] = -3.0e38f;
            } else {
                msk2[6][0] = -3.0e38f; msk2[6][1] = -3.0e38f;
                msk2[6][2] = -3.0e38f; msk2[6][3] = -3.0e38f;
            }
        }
        // hoisted Q fragments: heads (0,1) share k-window hg*64, (2,3) +32
        short8 q0 = *(const short8*)(R4 + (pt * 16 + lr) * KSTR + hg * 64 + lk);
        short8 q1 = *(const short8*)(R4 + (pt * 16 + lr) * KSTR + hg * 64 + 32 + lk);
        const int sA = ((lq & 1) << 5) + lr;        // src lane 2(lq&1)*16 + lr
        const int sB = sA + 16;
        const bool hisel = (lq >= 2);
        #pragma unroll
        for (int hh = 0; hh < 4; ++hh) {
            int h  = hg * 4 + hh;
            int k0 = hg * 64 + (hh >> 1) * 32;      // head's 32-wide k-window
            short8 bq = (hh < 2) ? q0 : q1;
            if ((lq >> 1) != (hh & 1)) bq = (short8){0,0,0,0,0,0,0,0};
            float sc[7][4];
            #pragma unroll
            for (int nt = 0; nt < 7; ++nt) {
                short8 ak = *(const short8*)(R2 + (nt * 16 + lr) * KSTR + k0 + lk);
                float4v cc = {msk2[nt][0], msk2[nt][1], msk2[nt][2], msk2[nt][3]};
                cc = __builtin_amdgcn_mfma_f32_16x16x32_bf16(ak, bq, cc, 0, 0, 0);
                #pragma unroll
                for (int r = 0; r < 4; ++r) sc[nt][r] = cc[r];
            }
            // ---- in-register softmax over n (tree max, 2+2 shfl total) ----
            float mm[7];
            #pragma unroll
            for (int nt = 0; nt < 7; ++nt)
                mm[nt] = fmaxf(fmaxf(sc[nt][0], sc[nt][1]),
                               fmaxf(sc[nt][2], sc[nt][3]));
            float m = fmaxf(fmaxf(fmaxf(mm[0], mm[1]), fmaxf(mm[2], mm[3])),
                            fmaxf(fmaxf(mm[4], mm[5]), mm[6]));
            m = fmaxf(m, __shfl_xor(m, 16));
            m = fmaxf(m, __shfl_xor(m, 32));
            float s0 = 0.f, s1 = 0.f, s2 = 0.f, s3 = 0.f;
            #pragma unroll
            for (int nt = 0; nt < 7; ++nt) {
                float e0 = EXP2(sc[nt][0] - m); sc[nt][0] = e0; s0 += e0;
                float e1 = EXP2(sc[nt][1] - m); sc[nt][1] = e1; s1 += e1;
                float e2 = EXP2(sc[nt][2] - m); sc[nt][2] = e2; s2 += e2;
                float e3 = EXP2(sc[nt][3] - m); sc[nt][3] = e3; s3 += e3;
            }
            float su = (s0 + s1) + (s2 + s3);
            su += __shfl_xor(su, 16);
            su += __shfl_xor(su, 32);
            float inv = RCP(su);                    // row inverse (lane-local)
            // pack normalized P (bf16 pairs); pd[7] = zero pad n=112..127
            uint32_t pd[8][2];
            #pragma unroll
            for (int nt = 0; nt < 7; ++nt) {
                pd[nt][0] = pk2(sc[nt][0] * inv, sc[nt][1] * inv);
                pd[nt][1] = pk2(sc[nt][2] * inv, sc[nt][3] * inv);
            }
            pd[7][0] = 0u; pd[7][1] = 0u;
            // PV with in-register A-fragments:
            // A[lr][32t+8lq+j]: dword dw from lane sA(+16 for dw>=2),
            //   register pd[2t + (lq>=2)][dw&1]  (select AFTER shuffle)
            float4v o = {0.f, 0.f, 0.f, 0.f};
            #pragma unroll
            for (int t = 0; t < 4; ++t) {
                uint32_t a0 = (uint32_t)__shfl((int)pd[2*t][0], sA);
                uint32_t a1 = (uint32_t)__shfl((int)pd[2*t][1], sA);
                uint32_t b0 = (uint32_t)__shfl((int)pd[2*t+1][0], sA);
                uint32_t b1 = (uint32_t)__shfl((int)pd[2*t+1][1], sA);
                uint32_t c0 = (uint32_t)__shfl((int)pd[2*t][0], sB);
                uint32_t c1 = (uint32_t)__shfl((int)pd[2*t][1], sB);
                uint32_t d0 = (uint32_t)__shfl((int)pd[2*t+1][0], sB);
                uint32_t d1 = (uint32_t)__shfl((int)pd[2*t+1][1], sB);
                union { uint32_t u[4]; short8 s; } af;
                af.u[0] = hisel ? b0 : a0;
                af.u[1] = hisel ? b1 : a1;
                af.u[2] = hisel ? d0 : c0;
                af.u[3] = hisel ? d1 : c1;
                short8 b2 = *(const short8*)(R3 + (h * 16 + lr) * KSTR + t * 32 + lk);
                o = __builtin_amdgcn_mfma_f32_16x16x32_bf16(af.s, b2, o, 0, 0, 0);
            }
            o4[hh] = o;
        }
    }
    __syncthreads();                                // all Q reads done

    // ---- O regs -> R4 (over Q); enc stays in R1 (no re-stage needed) ------
    if (wave < 14) {
        #pragma unroll
        for (int hh = 0; hh < 4; ++hh) {
            int h = hg * 4 + hh;
            #pragma unroll
            for (int r = 0; r < 4; ++r)
                R4[(pt * 16 + (lq << 2) + r) * KSTR + h * 16 + lr] = f2b(o4[hh][r]);
        }
    }
    __syncthreads();

    // ---- Phase E: mh = O@Wc + bc -> hi(R5)+lo(R2)  (cat, K dead) ----------
    {
        const int col = 16 * (wave & 7) + lr;
        const int mt0 = (wave >> 3) ? 4 : 0;
        const int mt1 = (wave >> 3) ? 7 : 4;
        short8 bw[4];
        {
            const bf16* rc = WcT + (size_t)col * 128 + lk;
            #pragma unroll
            for (int s = 0; s < 4; ++s) bw[s] = *(const short8*)(rc + s * 32);
        }
        float bcv = bc[col];
        for (int mt = mt0; mt < mt1; ++mt) {
            short8 a[4];
            #pragma unroll
            for (int s = 0; s < 4; ++s)
                a[s] = *(const short8*)(R4 + (mt * 16 + lr) * KSTR + s * 32 + lk);
            float4v c = {0.f, 0.f, 0.f, 0.f};
            #pragma unroll
            for (int s = 0; s < 4; ++s)
                c = __builtin_amdgcn_mfma_f32_16x16x32_bf16(a[s], bw[s], c, 0, 0, 0);
            int row0 = mt * 16 + (lq << 2);
            #pragma unroll
            for (int r = 0; r < 4; ++r) {           // two-term bf16 split of mh
                float m = c[r] + bcv;
                bf16 hb = f2b(m);
                R5[(row0 + r) * KSTR + col] = hb;
                R2[(row0 + r) * KSTR + col] = f2b(m - b2f(hb));
            }
        }
    }
    __syncthreads();

    // -------- Phase F: score2 swapped: lane holds S2[p=lr][n=16nt+4lq+r] ---
    // A = enc n-tiles (R1, still live), B = mh p-rows (hi R5 + lo R2);
    // msk2 reused from D. In-reg softmax (2+2 shfl), packed 16B stores.
    if (wave < 7) {
        const int pt2 = wave;                       // same p-rows as Phase D
        short8 bhi[4], blo[4];
        #pragma unroll
        for (int s = 0; s < 4; ++s) {
            bhi[s] = *(const short8*)(R5 + (pt2 * 16 + lr) * KSTR + s * 32 + lk);
            blo[s] = *(const short8*)(R2 + (pt2 * 16 + lr) * KSTR + s * 32 + lk);
        }
        float sc[7][4];
        #pragma unroll
        for (int nt = 0; nt < 7; ++nt) {
            float4v cc = {0.f, 0.f, 0.f, 0.f};
            #pragma unroll
            for (int s = 0; s < 4; ++s) {
                short8 ae = *(const short8*)(R1 + (nt * 16 + lr) * KSTR + s * 32 + lk);
                cc = __builtin_amdgcn_mfma_f32_16x16x32_bf16(ae, bhi[s], cc, 0, 0, 0);
                cc = __builtin_amdgcn_mfma_f32_16x16x32_bf16(ae, blo[s], cc, 0, 0, 0);
            }
            #pragma unroll
            for (int r = 0; r < 4; ++r) {
                // tanh via exp2 (const = 1/sqrt(128) * 2 * log2e)
                float y = EXP2(cc[r] * (0.08838834764831845f * 2.0f * L2E));
                float t = fmaf(-2.0f, RCP(y + 1.0f), 1.0f);
                // log2e*(10*tanh + mask)   (msk2 already pre-scaled)
                sc[nt][r] = fmaf(10.0f * L2E, t, msk2[nt][r]);
            }
        }
        // in-register softmax over n
        float mm[7];
        #pragma unroll
        for (int nt = 0; nt < 7; ++nt)
            mm[nt] = fmaxf(fmaxf(sc[nt][0], sc[nt][1]),
                           fmaxf(sc[nt][2], sc[nt][3]));
        float m = fmaxf(fmaxf(fmaxf(mm[0], mm[1]), fmaxf(mm[2], mm[3])),
                        fmaxf(fmaxf(mm[4], mm[5]), mm[6]));
        m = fmaxf(m, __shfl_xor(m, 16));
        m = fmaxf(m, __shfl_xor(m, 32));
        float s0 = 0.f, s1 = 0.f, s2 = 0.f, s3 = 0.f;
        #pragma unroll
        for (int nt = 0; nt < 7; ++nt) {
            float e0 = EXP2(sc[nt][0] - m); sc[nt][0] = e0; s0 += e0;
            float e1 = EXP2(sc[nt][1] - m); sc[nt][1] = e1; s1 += e1;
            float e2 = EXP2(sc[nt][2] - m); sc[nt][2] = e2; s2 += e2;
            float e3 = EXP2(sc[nt][3] - m); sc[nt][3] = e3; s3 += e3;
        }
        float su = (s0 + s1) + (s2 + s3);
        su += __shfl_xor(su, 16);
        su += __shfl_xor(su, 32);
        float inv = RCP(su);
        const int p = pt2 * 16 + lr;
        if (p < P_) {
            float* orow = outB + (size_t)p * N_;
            #pragma unroll
            for (int nt = 0; nt < 6; ++nt) {
                F4 ov = { sc[nt][0] * inv, sc[nt][1] * inv,
                          sc[nt][2] * inv, sc[nt][3] * inv };
                *(F4*)(orow + nt * 16 + (lq << 2)) = ov;
            }
            if (lq == 0) {
                F4 ov = { sc[6][0] * inv, sc[6][1] * inv,
                          sc[6][2] * inv, sc[6][3] * inv };
                *(F4*)(orow + 96) = ov;
            } else if (lq == 1) {
                orow[100] = sc[6][0] * inv;
            }
        }
    }
}

extern "C" void kernel_launch(void* const* d_in, const int* in_sizes, int n_in,
                              void* d_out, int out_size, void* d_ws, size_t ws_size,
                              hipStream_t stream) {
    const float* eln   = (const float*)d_in[0];
    const float* load_ = (const float*)d_in[1];
    const float* time_ = (const float*)d_in[2];
    const float* len_  = (const float*)d_in[3];
    const float* open_ = (const float*)d_in[4];
    const float* mask_ = (const float*)d_in[5];
    const float* enc_  = (const float*)d_in[6];
    const float* Wq    = (const float*)d_in[7];
    const float* Wk    = (const float*)d_in[8];
    const float* Wv    = (const float*)d_in[9];
    const float* Wc    = (const float*)d_in[10];
    const float* bc    = (const float*)d_in[11];
    float* out = (float*)d_out;
    bf16* wsWT = (bf16*)d_ws;                      // 4*16384*2 = 131072 B

    prep_wT<<<dim3(256), dim3(256), 0, stream>>>(Wq, Wk, Wv, Wc, wsWT);
    vrp_kernel<<<dim3(B_), dim3(1024), 0, stream>>>(
        eln, load_, time_, len_, open_, mask_, enc_, Wq, bc, wsWT, out);
}

// Round 8
// 271.367 us; speedup vs baseline: 1.0172x; 1.0172x over previous
//
#include <hip/hip_runtime.h>
#include <stdint.h>

#define B_    1024
#define P_    100
#define N_    101
#define EMB_  128
#define H_    8
#define DK_   16

#define ROWS  112          // 7 m-tiles of 16 (covers P=100 / N=101)
#define KSTR  136          // LDS row stride in bf16 elems

typedef uint16_t bf16;
typedef __attribute__((ext_vector_type(8))) short short8;
typedef __attribute__((ext_vector_type(4))) float float4v;

struct F4 { float x, y, z, w; };   // 4-byte-aligned float quad (101-stride safe)

#define L2E 1.4426950408889634f

#if __has_builtin(__builtin_amdgcn_exp2f)
#define EXP2(x) __builtin_amdgcn_exp2f(x)
#else
#define EXP2(x) exp2f(x)
#endif
#if __has_builtin(__builtin_amdgcn_rcpf)
#define RCP(x) __builtin_amdgcn_rcpf(x)
#else
#define RCP(x) (1.0f / (x))
#endif

__device__ __forceinline__ float b2f(bf16 u) {
    union { uint32_t i; float f; } c; c.i = ((uint32_t)u) << 16; return c.f;
}
// round-half-up f32->bf16 (bias then take high 16): 2 ops
__device__ __forceinline__ bf16 f2b(float f) {
    union { float f; uint32_t i; } c; c.f = f;
    return (bf16)((c.i + 0x8000u) >> 16);
}
// packed pair via v_perm byte-select: 3 ops for 2 values
__device__ __forceinline__ uint32_t pk2(float a, float b) {
    union { float f; uint32_t i; } ca, cb; ca.f = a; cb.f = b;
    return __builtin_amdgcn_perm(cb.i + 0x8000u, ca.i + 0x8000u, 0x07060302u);
}

// stage f32 [nrows][128] row-major -> bf16 LDS [ROWS][KSTR], zero pad rows
__device__ __forceinline__ void stage_m(const float* __restrict__ src, int nrows,
                                        bf16* __restrict__ dst, int tid) {
    for (int i = tid; i < ROWS * 32; i += 1024) {
        int r = i >> 5, c = (i & 31) << 2;
        uint32_t p0 = 0, p1 = 0;
        if (r < nrows) {
            float4 v = *(const float4*)(src + (size_t)r * EMB_ + c);
            p0 = pk2(v.x, v.y); p1 = pk2(v.z, v.w);
        }
        uint32_t* d = (uint32_t*)(dst + r * KSTR + c);
        d[0] = p0; d[1] = p1;
    }
}

// ---- prep: W f32 [k][o] -> ws bf16 W^T [o][k], order: Wk, Wv, Wq, Wc ------
__global__ __launch_bounds__(256)
void prep_wT(const float* __restrict__ Wq, const float* __restrict__ Wk,
             const float* __restrict__ Wv, const float* __restrict__ Wc,
             bf16* __restrict__ ws) {
    int idx = blockIdx.x * 256 + threadIdx.x;      // 65536 threads
    int w = idx >> 14, rem = idx & 16383;
    int k = rem >> 7, o = rem & 127;               // o innermost: coalesced read
    const float* W = (w == 0) ? Wk : (w == 1) ? Wv : (w == 2) ? Wq : Wc;
    ws[((size_t)w << 14) + o * 128 + k] = f2b(W[(size_t)k * 128 + o]);
}

__global__ __launch_bounds__(1024, 4)
void vrp_kernel(const float* __restrict__ eln,
                const float* __restrict__ load_,
                const float* __restrict__ time_,
                const float* __restrict__ len_,
                const float* __restrict__ open_,
                const float* __restrict__ mask_,
                const float* __restrict__ enc_,
                const float* __restrict__ Wq,
                const float* __restrict__ bc,
                const bf16* __restrict__ wsWT,
                float* __restrict__ out)
{
    const int b    = blockIdx.x;
    const int tid  = threadIdx.x;
    const int wave = tid >> 6;
    const int lane = tid & 63;
    const int lr = lane & 15, lq = lane >> 4, lk = lq << 3;

    // Overlays: R1 enc (live to F) ; R2 K/mh-lo ; R3 V^T ;
    //           R4 Q/P(hg=1)/O ; R5 cat/P(hg=0)/mh-hi
    __shared__ bf16 smem[78336];
    __shared__ float sS4[ROWS * 4];
    __shared__ float sWq4[4 * EMB_];
    bf16* const R1 = smem;
    bf16* const R2 = smem + 15232;
    bf16* const R3 = smem + 30464;
    bf16* const R4 = smem + 47872;
    bf16* const R5 = smem + 63104;

    const bf16* WkT = wsWT;
    const bf16* WvT = wsWT + 16384;
    const bf16* WqT = wsWT + 32768;
    const bf16* WcT = wsWT + 49152;

    const float* encB  = enc_  + (size_t)b * N_ * EMB_;
    const float* elnB  = eln   + (size_t)b * P_ * EMB_;
    const float* maskB = mask_ + (size_t)b * P_ * N_;
    float*       outB  = out   + (size_t)b * P_ * N_;

    // ---------------- Phase A: stage enc->R1, cat->R5, extras --------------
    stage_m(encB, N_, R1, tid);
    stage_m(elnB, P_, R5, tid);
    if (tid < 512) {   // zero sVt[d][112..127]
        int d = tid >> 2, c = 112 + ((tid & 3) << 2);
        uint32_t* z = (uint32_t*)(R3 + d * KSTR + c);
        z[0] = 0; z[1] = 0;
    }
    if (tid < ROWS * 4) {
        int r = tid >> 2, j = tid & 3;
        float v = 0.f;
        if (r < P_) {
            const float* s4 = (j == 0) ? load_ : (j == 1) ? time_
                             : (j == 2) ? len_ : open_;
            v = s4[(size_t)b * P_ + r];
        }
        sS4[r * 4 + j] = v;
    }
    if (tid < 512) {
        int j = tid >> 7, c = tid & 127;
        sWq4[j * EMB_ + c] = Wq[(size_t)(EMB_ + j) * EMB_ + c];
    }
    __syncthreads();

    // ------- Phase B+C: K->R2, V^T->R3, Q'->R4 (one barrier window) --------
    // 16 waves = 8 col-tiles x 2 m-tile halves
    {
        const int col = 16 * (wave & 7) + lr;
        const int mt0 = (wave >> 3) ? 4 : 0;
        const int mt1 = (wave >> 3) ? 7 : 4;
        short8 bk[4], bv[4], bq[4];
        {
            const bf16* rk = WkT + (size_t)col * 128 + lk;
            const bf16* rv = WvT + (size_t)col * 128 + lk;
            const bf16* rq = WqT + (size_t)col * 128 + lk;
            #pragma unroll
            for (int s = 0; s < 4; ++s) {
                bk[s] = *(const short8*)(rk + s * 32);
                bv[s] = *(const short8*)(rv + s * 32);
                bq[s] = *(const short8*)(rq + s * 32);
            }
        }
        float w0 = sWq4[col], w1 = sWq4[EMB_ + col];
        float w2 = sWq4[2 * EMB_ + col], w3 = sWq4[3 * EMB_ + col];
        for (int mt = mt0; mt < mt1; ++mt) {
            short8 a[4];
            #pragma unroll
            for (int s = 0; s < 4; ++s)
                a[s] = *(const short8*)(R1 + (mt * 16 + lr) * KSTR + s * 32 + lk);
            float4v ck = {0.f, 0.f, 0.f, 0.f}, cv = {0.f, 0.f, 0.f, 0.f};
            #pragma unroll
            for (int s = 0; s < 4; ++s) {
                ck = __builtin_amdgcn_mfma_f32_16x16x32_bf16(a[s], bk[s], ck, 0, 0, 0);
                cv = __builtin_amdgcn_mfma_f32_16x16x32_bf16(a[s], bv[s], cv, 0, 0, 0);
            }
            int n0 = mt * 16 + (lq << 2);
            #pragma unroll
            for (int r = 0; r < 4; ++r)
                R2[(n0 + r) * KSTR + col] = f2b(ck[r]);       // K [n][col]
            uint32_t* d = (uint32_t*)(R3 + col * KSTR + n0);  // V^T [d][n]
            d[0] = pk2(cv[0], cv[1]);
            d[1] = pk2(cv[2], cv[3]);
            // Q' = 0.25*log2e*(cat@Wq) for same mt  (log2e baked for exp2)
            short8 aq[4];
            #pragma unroll
            for (int s = 0; s < 4; ++s)
                aq[s] = *(const short8*)(R5 + (mt * 16 + lr) * KSTR + s * 32 + lk);
            float4v cq = {0.f, 0.f, 0.f, 0.f};
            #pragma unroll
            for (int s = 0; s < 4; ++s)
                cq = __builtin_amdgcn_mfma_f32_16x16x32_bf16(aq[s], bq[s], cq, 0, 0, 0);
            int row0 = mt * 16 + (lq << 2);
            #pragma unroll
            for (int r = 0; r < 4; ++r) {
                const float* s4 = sS4 + (row0 + r) * 4;
                float acc = cq[r] + s4[0] * w0 + s4[1] * w1 + s4[2] * w2 + s4[3] * w3;
                R4[(row0 + r) * KSTR + col] = f2b(acc * (0.25f * L2E));
            }
        }
    }
    __syncthreads();

    // -------- Phase D: attention; 14 waves = 7 p-tiles x 2 head-groups -----
    // Swapped QK^T: lane holds P[row=pt*16+lr][n=16nt+4lq+r] in registers.
    // P->LDS roundtrip for PV (proven faster than shuffle assembly, r6 vs r7).
    // P buffers: hg=0 -> R5 (cat dead), hg=1 -> R4 (Q dead after hoist+barrier)
    // so enc stays live in R1 for Phase F (no re-stage).
    const int hg = (wave >= 7) ? 1 : 0;
    const int pt = wave - hg * 7;
    float msk2[7][4];                 // reused by Phase F (waves 0-6)
    float4v o4[4];
    short8 q0, q1;
    if (wave < 14) {
        // mask gather in swapped layout: row p = pt*16+lr, n = 16nt+4lq+r
        {
            const int p = pt * 16 + lr;
            const bool pvalid = (p < P_);
            const float* mrow = maskB + (size_t)(pvalid ? p : 0) * N_;
            #pragma unroll
            for (int nt = 0; nt < 6; ++nt) {        // n <= 95 < 101: packed
                int nb = nt * 16 + (lq << 2);
                F4 mv = *(const F4*)(mrow + nb);
                msk2[nt][0] = pvalid ? mv.x * L2E : 0.f;
                msk2[nt][1] = pvalid ? mv.y * L2E : 0.f;
                msk2[nt][2] = pvalid ? mv.z * L2E : 0.f;
                msk2[nt][3] = pvalid ? mv.w * L2E : 0.f;
            }
            // nt=6 tail: n = 96+4lq+r, valid only n<=100
            if (lq == 0) {
                F4 mv = *(const F4*)(mrow + 96);
                msk2[6][0] = pvalid ? mv.x * L2E : 0.f;
                msk2[6][1] = pvalid ? mv.y * L2E : 0.f;
                msk2[6][2] = pvalid ? mv.z * L2E : 0.f;
                msk2[6][3] = pvalid ? mv.w * L2E : 0.f;
            } else if (lq == 1) {
                msk2[6][0] = pvalid ? mrow[100] * L2E : 0.f;
                msk2[6][1] = -3.0e38f; msk2[6][2] = -3.0e38f; msk2[6][3] = -3.0e38f;
            } else {
                msk2[6][0] = -3.0e38f; msk2[6][1] = -3.0e38f;
                msk2[6][2] = -3.0e38f; msk2[6][3] = -3.0e38f;
            }
        }
        // hoisted Q fragments: heads (0,1) share k-window hg*64, (2,3) +32
        q0 = *(const short8*)(R4 + (pt * 16 + lr) * KSTR + hg * 64 + lk);
        q1 = *(const short8*)(R4 + (pt * 16 + lr) * KSTR + hg * 64 + 32 + lk);
    }
    __syncthreads();                  // Q fully consumed -> R4/R5 become P bufs
    if (wave < 14) {
        bf16* Pbuf = hg ? R4 : R5;
        {   // zero pad cols 112..127 of my p-tile rows
            uint32_t* z = (uint32_t*)(Pbuf + (pt * 16 + lr) * KSTR + 112 + (lq << 2));
            z[0] = 0; z[1] = 0;
        }
        #pragma unroll
        for (int hh = 0; hh < 4; ++hh) {
            int h  = hg * 4 + hh;
            int k0 = hg * 64 + (hh >> 1) * 32;      // head's 32-wide k-window
            short8 bq = (hh < 2) ? q0 : q1;
            if ((lq >> 1) != (hh & 1)) bq = (short8){0,0,0,0,0,0,0,0};
            float sc[7][4];
            #pragma unroll
            for (int nt = 0; nt < 7; ++nt) {
                short8 ak = *(const short8*)(R2 + (nt * 16 + lr) * KSTR + k0 + lk);
                float4v cc = {msk2[nt][0], msk2[nt][1], msk2[nt][2], msk2[nt][3]};
                cc = __builtin_amdgcn_mfma_f32_16x16x32_bf16(ak, bq, cc, 0, 0, 0);
                #pragma unroll
                for (int r = 0; r < 4; ++r) sc[nt][r] = cc[r];
            }
            // ---- in-register softmax over n (tree max, 2+2 shfl total) ----
            float mm[7];
            #pragma unroll
            for (int nt = 0; nt < 7; ++nt)
                mm[nt] = fmaxf(fmaxf(sc[nt][0], sc[nt][1]),
                               fmaxf(sc[nt][2], sc[nt][3]));
            float m = fmaxf(fmaxf(fmaxf(mm[0], mm[1]), fmaxf(mm[2], mm[3])),
                            fmaxf(fmaxf(mm[4], mm[5]), mm[6]));
            m = fmaxf(m, __shfl_xor(m, 16));
            m = fmaxf(m, __shfl_xor(m, 32));
            float s0 = 0.f, s1 = 0.f, s2 = 0.f, s3 = 0.f;
            #pragma unroll
            for (int nt = 0; nt < 7; ++nt) {
                float e0 = EXP2(sc[nt][0] - m); sc[nt][0] = e0; s0 += e0;
                float e1 = EXP2(sc[nt][1] - m); sc[nt][1] = e1; s1 += e1;
                float e2 = EXP2(sc[nt][2] - m); sc[nt][2] = e2; s2 += e2;
                float e3 = EXP2(sc[nt][3] - m); sc[nt][3] = e3; s3 += e3;
            }
            float su = (s0 + s1) + (s2 + s3);
            su += __shfl_xor(su, 16);
            su += __shfl_xor(su, 32);
            float inv = RCP(su);                    // row inverse (lane-local)
            // P (normalized) -> LDS, packed b64 per nt (A-layout rows p=lr)
            #pragma unroll
            for (int nt = 0; nt < 7; ++nt) {
                uint32_t* d = (uint32_t*)(Pbuf + (pt * 16 + lr) * KSTR
                                          + nt * 16 + (lq << 2));
                d[0] = pk2(sc[nt][0] * inv, sc[nt][1] * inv);
                d[1] = pk2(sc[nt][2] * inv, sc[nt][3] * inv);
            }
            float4v o = {0.f, 0.f, 0.f, 0.f};       // PV -> registers
            #pragma unroll
            for (int ks = 0; ks < 128; ks += 32) {
                short8 a2 = *(const short8*)(Pbuf + (pt * 16 + lr) * KSTR + ks + lk);
                short8 b2 = *(const short8*)(R3 + (h * 16 + lr) * KSTR + ks + lk);
                o = __builtin_amdgcn_mfma_f32_16x16x32_bf16(a2, b2, o, 0, 0, 0);
            }
            o4[hh] = o;
        }
    }
    __syncthreads();                                // all P reads done

    // ---- O regs -> R4 (over P/Q); enc stays in R1 (no re-stage) -----------
    if (wave < 14) {
        #pragma unroll
        for (int hh = 0; hh < 4; ++hh) {
            int h = hg * 4 + hh;
            #pragma unroll
            for (int r = 0; r < 4; ++r)
                R4[(pt * 16 + (lq << 2) + r) * KSTR + h * 16 + lr] = f2b(o4[hh][r]);
        }
    }
    __syncthreads();

    // ---- Phase E: mh = O@Wc + bc -> hi(R5)+lo(R2)  (cat/P, K dead) --------
    {
        const int col = 16 * (wave & 7) + lr;
        const int mt0 = (wave >> 3) ? 4 : 0;
        const int mt1 = (wave >> 3) ? 7 : 4;
        short8 bw[4];
        {
            const bf16* rc = WcT + (size_t)col * 128 + lk;
            #pragma unroll
            for (int s = 0; s < 4; ++s) bw[s] = *(const short8*)(rc + s * 32);
        }
        float bcv = bc[col];
        for (int mt = mt0; mt < mt1; ++mt) {
            short8 a[4];
            #pragma unroll
            for (int s = 0; s < 4; ++s)
                a[s] = *(const short8*)(R4 + (mt * 16 + lr) * KSTR + s * 32 + lk);
            float4v c = {0.f, 0.f, 0.f, 0.f};
            #pragma unroll
            for (int s = 0; s < 4; ++s)
                c = __builtin_amdgcn_mfma_f32_16x16x32_bf16(a[s], bw[s], c, 0, 0, 0);
            int row0 = mt * 16 + (lq << 2);
            #pragma unroll
            for (int r = 0; r < 4; ++r) {           // two-term bf16 split of mh
                float m = c[r] + bcv;
                bf16 hb = f2b(m);
                R5[(row0 + r) * KSTR + col] = hb;
                R2[(row0 + r) * KSTR + col] = f2b(m - b2f(hb));
            }
        }
    }
    __syncthreads();

    // -------- Phase F: score2 swapped: lane holds S2[p=lr][n=16nt+4lq+r] ---
    // A = enc n-tiles (R1, still live), B = mh p-rows (hi R5 + lo R2);
    // msk2 reused from D. Softmax uses CONSTANT max 10*log2e (tanh-bounded:
    // score2 <= 10, so exp2(sc - 10*L2E) in [2^-29, 1] -- no max pass).
    if (wave < 7) {
        const int pt2 = wave;                       // same p-rows as Phase D
        short8 bhi[4], blo[4];
        #pragma unroll
        for (int s = 0; s < 4; ++s) {
            bhi[s] = *(const short8*)(R5 + (pt2 * 16 + lr) * KSTR + s * 32 + lk);
            blo[s] = *(const short8*)(R2 + (pt2 * 16 + lr) * KSTR + s * 32 + lk);
        }
        float sc[7][4];
        #pragma unroll
        for (int nt = 0; nt < 7; ++nt) {
            float4v cc = {0.f, 0.f, 0.f, 0.f};
            #pragma unroll
            for (int s = 0; s < 4; ++s) {
                short8 ae = *(const short8*)(R1 + (nt * 16 + lr) * KSTR + s * 32 + lk);
                cc = __builtin_amdgcn_mfma_f32_16x16x32_bf16(ae, bhi[s], cc, 0, 0, 0);
                cc = __builtin_amdgcn_mfma_f32_16x16x32_bf16(ae, blo[s], cc, 0, 0, 0);
            }
            #pragma unroll
            for (int r = 0; r < 4; ++r) {
                // tanh via exp2 (const = 1/sqrt(128) * 2 * log2e)
                float y = EXP2(cc[r] * (0.08838834764831845f * 2.0f * L2E));
                float t = fmaf(-2.0f, RCP(y + 1.0f), 1.0f);
                // log2e*(10*tanh + mask)   (msk2 already pre-scaled)
                sc[nt][r] = fmaf(10.0f * L2E, t, msk2[nt][r]);
            }
        }
        // softmax over n with constant max (score2 bounded by +10)
        const float mF = 10.0f * L2E;
        float s0 = 0.f, s1 = 0.f, s2 = 0.f, s3 = 0.f;
        #pragma unroll
        for (int nt = 0; nt < 7; ++nt) {
            float e0 = EXP2(sc[nt][0] - mF); sc[nt][0] = e0; s0 += e0;
            float e1 = EXP2(sc[nt][1] - mF); sc[nt][1] = e1; s1 += e1;
            float e2 = EXP2(sc[nt][2] - mF); sc[nt][2] = e2; s2 += e2;
            float e3 = EXP2(sc[nt][3] - mF); sc[nt][3] = e3; s3 += e3;
        }
        float su = (s0 + s1) + (s2 + s3);
        su += __shfl_xor(su, 16);
        su += __shfl_xor(su, 32);
        float inv = RCP(su);
        const int p = pt2 * 16 + lr;
        if (p < P_) {
            float* orow = outB + (size_t)p * N_;
            #pragma unroll
            for (int nt = 0; nt < 6; ++nt) {
                F4 ov = { sc[nt][0] * inv, sc[nt][1] * inv,
                          sc[nt][2] * inv, sc[nt][3] * inv };
                *(F4*)(orow + nt * 16 + (lq << 2)) = ov;
            }
            if (lq == 0) {
                F4 ov = { sc[6][0] * inv, sc[6][1] * inv,
                          sc[6][2] * inv, sc[6][3] * inv };
                *(F4*)(orow + 96) = ov;
            } else if (lq == 1) {
                orow[100] = sc[6][0] * inv;
            }
        }
    }
}

extern "C" void kernel_launch(void* const* d_in, const int* in_sizes, int n_in,
                              void* d_out, int out_size, void* d_ws, size_t ws_size,
                              hipStream_t stream) {
    const float* eln   = (const float*)d_in[0];
    const float* load_ = (const float*)d_in[1];
    const float* time_ = (const float*)d_in[2];
    const float* len_  = (const float*)d_in[3];
    const float* open_ = (const float*)d_in[4];
    const float* mask_ = (const float*)d_in[5];
    const float* enc_  = (const float*)d_in[6];
    const float* Wq    = (const float*)d_in[7];
    const float* Wk    = (const float*)d_in[8];
    const float* Wv    = (const float*)d_in[9];
    const float* Wc    = (const float*)d_in[10];
    const float* bc    = (const float*)d_in[11];
    float* out = (float*)d_out;
    bf16* wsWT = (bf16*)d_ws;                      // 4*16384*2 = 131072 B

    prep_wT<<<dim3(256), dim3(256), 0, stream>>>(Wq, Wk, Wv, Wc, wsWT);
    vrp_kernel<<<dim3(B_), dim3(1024), 0, stream>>>(
        eln, load_, time_, len_, open_, mask_, enc_, Wq, bc, wsWT, out);
}